// Round 9
// baseline (238.762 us; speedup 1.0000x reference)
//
#include <hip/hip_runtime.h>
#include <math.h>

typedef _Float16 half8 __attribute__((ext_vector_type(8)));
typedef _Float16 half4v __attribute__((ext_vector_type(4)));
typedef float floatx4 __attribute__((ext_vector_type(4)));

union U16 { uint4 u; half8 h; };

// ---------------------------------------------------------------------------
// k_prep: 1029 blocks x 256 thr. K-split partials + last-block-wins reduce
// (replaces the old prep1 + prep2 pair; one launch, one less gap).
//  [0,512):     R partials: dg=bid>>3 (64 groups x 4 d-rows), kq=bid&7 (K=128)
//               last of 8 blocks per dg reduces its 4 rows (kq ascending ->
//               bit-identical to old prep2).
//  [512,1024):  a/bv partials: rg (128 groups x 4 rows), kq&3 (K=64);
//               last of 4 reduces.
//  [1024,1028): WmT2 pack granules (f16)
//  [1028]:      WoPk pack granules (f16)
// Ticket pattern per G16: stores -> __threadfence (release) -> syncthreads ->
// tid0 atomicAdd -> syncthreads -> last block __threadfence (acquire) -> read.
// ---------------------------------------------------------------------------
__global__ __launch_bounds__(256) void k_prep(
    const float* __restrict__ hs, const float* __restrict__ Wh,
    const float* __restrict__ Wo,
    float* __restrict__ Rp, float* __restrict__ ap, float* __restrict__ bp,
    float* __restrict__ R, float* __restrict__ a, float* __restrict__ bv,
    uint4* __restrict__ WmT2, uint4* __restrict__ WoPk, int* __restrict__ cnt)
{
  __shared__ __align__(16) char pool[32768];
  __shared__ int lastFlag;
  int bid = blockIdx.x, tid = threadIdx.x;

  if (bid < 512) {                       // ---- R partials + reduce ----
    float (*tbl)[4] = (float(*)[4])pool; // [128 k][4 d]
    int dg = bid >> 3, kq = bid & 7, d0 = dg * 4, k0 = kq * 128;
    for (int idx = tid; idx < 512; idx += 256) {
      int t = idx >> 2, dl = idx & 3;
      int k = k0 + t;
      float e = (float)(k & ~1) * (1.0f / 1024.f);
      float div = powf(10000.f, e);
      float ang = (float)(d0 + dl) / div;
      tbl[t][dl] = (k & 1) ? cosf(ang) : sinf(ang);
    }
    __syncthreads();
    int h = tid;
    float acc[4] = {0, 0, 0, 0};
    for (int kk = 0; kk < 128; ++kk) {
      float wv = Wh[(k0 + kk) * 256 + h];
      float4 tr = *(const float4*)&tbl[kk][0];
      acc[0] = fmaf(tr.x, wv, acc[0]);
      acc[1] = fmaf(tr.y, wv, acc[1]);
      acc[2] = fmaf(tr.z, wv, acc[2]);
      acc[3] = fmaf(tr.w, wv, acc[3]);
    }
#pragma unroll
    for (int dl = 0; dl < 4; ++dl)
      Rp[kq * 65536 + (d0 + dl) * 256 + h] = acc[dl];  // d=255 row unused

    __threadfence();                     // release partials device-wide
    __syncthreads();
    if (tid == 0) lastFlag = (atomicAdd(&cnt[dg], 1) == 7);
    __syncthreads();
    if (lastFlag) {
      __threadfence();                   // acquire other blocks' partials
#pragma unroll
      for (int dl = 0; dl < 4; ++dl) {
        int d = d0 + dl;
        float s = 0.f;
#pragma unroll
        for (int q = 0; q < 8; ++q) s += Rp[q * 65536 + d * 256 + h];
        R[d * 256 + h] = s;
      }
    }

  } else if (bid < 1024) {               // ---- a / bv partials + reduce ----
    float (*xs)[4] = (float(*)[4])pool;  // [64 k][4 r]
    int g = bid - 512, rg = g >> 2, kq = g & 3;
    int r0 = rg * 4, k0 = kq * 64;
    {
      int r = tid >> 6, kk = tid & 63;
      xs[kk][r] = hs[(size_t)(r0 + r) * 256 + k0 + kk];
    }
    __syncthreads();
    int h = tid;
    float aa[4] = {0, 0, 0, 0}, bb[4] = {0, 0, 0, 0};
    for (int kk = 0; kk < 64; ++kk) {
      int k = k0 + kk;
      float we = Wh[k * 256 + h];
      float wsv = Wh[(256 + k) * 256 + h];
      float wd = Wh[(512 + k) * 256 + h];
      float wA = we + wd, wB = wsv - wd;
      float4 xr = *(const float4*)&xs[kk][0];
      aa[0] = fmaf(xr.x, wA, aa[0]);  bb[0] = fmaf(xr.x, wB, bb[0]);
      aa[1] = fmaf(xr.y, wA, aa[1]);  bb[1] = fmaf(xr.y, wB, bb[1]);
      aa[2] = fmaf(xr.z, wA, aa[2]);  bb[2] = fmaf(xr.z, wB, bb[2]);
      aa[3] = fmaf(xr.w, wA, aa[3]);  bb[3] = fmaf(xr.w, wB, bb[3]);
    }
#pragma unroll
    for (int r = 0; r < 4; ++r) {
      ap[kq * 131072 + (r0 + r) * 256 + h] = aa[r];
      bp[kq * 131072 + (r0 + r) * 256 + h] = bb[r];
    }

    __threadfence();
    __syncthreads();
    if (tid == 0) lastFlag = (atomicAdd(&cnt[64 + rg], 1) == 3);
    __syncthreads();
    if (lastFlag) {
      __threadfence();
#pragma unroll
      for (int r = 0; r < 4; ++r) {
        float sa = 0.f, sb = 0.f;
#pragma unroll
        for (int q = 0; q < 4; ++q) {
          sa += ap[q * 131072 + (r0 + r) * 256 + h];
          sb += bp[q * 131072 + (r0 + r) * 256 + h];
        }
        a[(size_t)(r0 + r) * 256 + h] = sa;
        bv[(size_t)(r0 + r) * 256 + h] = sb;
      }
    }

  } else if (bid < 1028) {               // ---- WmT2 pack ----
    _Float16 (*T)[256] = (_Float16(*)[256])pool; // [64 k][256 h]
    int q = bid - 1024;
    for (int idx = tid; idx < 16384; idx += 256) {
      int k = idx >> 8, h = idx & 255;
      T[k][h] = (_Float16)Wh[(768 + q * 64 + k) * 256 + h];
    }
    __syncthreads();
    for (int gi = tid; gi < 2048; gi += 256) {
      int kbl = gi >> 8, h = gi & 255;
      U16 v;
#pragma unroll
      for (int e = 0; e < 8; ++e) v.h[e] = T[kbl * 8 + e][h];
      WmT2[(q * 8 + kbl) * 256 + h] = v.u;
    }

  } else {                               // ---- WoPk pack ----
    for (int gi = tid; gi < 512; gi += 256) {
      int kb = gi >> 4, c = gi & 15;
      U16 v;
#pragma unroll
      for (int e = 0; e < 8; ++e)
        v.h[e] = (c < 5) ? (_Float16)Wo[(kb * 8 + e) * 5 + c] : (_Float16)0.f;
      WoPk[gi] = v.u;
    }
  }
}

// ---------------------------------------------------------------------------
// main: 2048 blocks = (b, i, j-tile 64); 4 waves, wave w owns h' [64w,64w+64).
// Proven R2 structure (staged coalesced init, padded LDS 34304, bounds(256,4))
// + 1-deep ping-pong B-frag prefetch (neutral per R8, kept).
// [R7 lesson: per-lane float4 gathers of bv/R are 1KB-strided -> over-fetch +
//  scratch; init must stay cooperatively staged.
//  R4 lesson: min-waves=5 caps VGPR at 96 -> spill; stay at (256,4).]
// ---------------------------------------------------------------------------
__global__ __launch_bounds__(256, 4) void k_main(
    const float* __restrict__ hs, const int* __restrict__ mask,
    const float* __restrict__ R, const float* __restrict__ a,
    const float* __restrict__ bvec, const float* __restrict__ Whb,
    const uint4* __restrict__ WmT2, const uint4* __restrict__ WoPk,
    const float* __restrict__ Wob, float* __restrict__ out)
{
  __shared__ __align__(16) char smem[34304];          // max(34304, 33792)
  _Float16 (*As)[264] = (_Float16(*)[264])smem;       // [64][264] f16, 33792 B
  float (*stg)[268] = (float(*)[268])smem;            // [32][268] f32, 34304 B

  int bid = blockIdx.x, tid = threadIdx.x;
  int jt = bid & 3, i = (bid >> 2) & 255, b = bid >> 10;
  int j0 = jt * 64;
  int lane = tid & 63, w = tid >> 6;
  int c16 = lane & 15, quad = lane >> 4;
  const float* hsb = hs + (size_t)b * 65536;

  // ---- per-thread constant part of init: a_i + bias ----
  float av[4];
#pragma unroll
  for (int ht2 = 0; ht2 < 4; ++ht2) {
    int hp = 64 * w + 16 * ht2 + c16;
    av[ht2] = a[((size_t)(b * 256 + i)) * 256 + hp] + Whb[hp];
  }

  // ---- acc init via LDS-staged (bv_j + R_d), two 32-row halves ----
  floatx4 acc[4][4];
#pragma unroll
  for (int hf = 0; hf < 2; ++hf) {
    int jbase = j0 + hf * 32;
#pragma unroll
    for (int it = 0; it < 8; ++it) {
      int idx = it * 256 + tid;
      int row = idx >> 6;            // 0..31
      int c4 = (idx & 63) << 2;      // 0..252 step 4
      int jg = jbase + row;
      int dd = jg - i;
      dd = dd < -127 ? -127 : (dd > 127 ? 127 : dd);
      dd += 127;
      float4 bb = *(const float4*)(bvec + ((size_t)(b * 256 + jg)) * 256 + c4);
      float4 rr = *(const float4*)(R + (size_t)dd * 256 + c4);
      float4 s;
      s.x = bb.x + rr.x; s.y = bb.y + rr.y;
      s.z = bb.z + rr.z; s.w = bb.w + rr.w;
      *(float4*)&stg[row][c4] = s;
    }
    __syncthreads();
#pragma unroll
    for (int jj = 0; jj < 2; ++jj) {
      int jt2 = hf * 2 + jj;
#pragma unroll
      for (int r = 0; r < 4; ++r) {
        int jl32 = jj * 16 + quad * 4 + r;
#pragma unroll
        for (int ht2 = 0; ht2 < 4; ++ht2)
          acc[jt2][ht2][r] = av[ht2] + stg[jl32][64 * w + 16 * ht2 + c16];
      }
    }
    __syncthreads();  // stg reads done before next stage / A-tile overwrite
  }

  // ---- A tile: As[j][k] = f16(x_i[k] * x_j[k]), 16B granules ----
  {
    int k8 = (tid & 31) * 8;
    float4 xi0 = *(const float4*)(hsb + i * 256 + k8);
    float4 xi1 = *(const float4*)(hsb + i * 256 + k8 + 4);
    int j = tid >> 5;  // 0..7
#pragma unroll
    for (int s = 0; s < 8; ++s, j += 8) {
      float4 xj0 = *(const float4*)(hsb + (j0 + j) * 256 + k8);
      float4 xj1 = *(const float4*)(hsb + (j0 + j) * 256 + k8 + 4);
      half8 p = {(_Float16)(xi0.x * xj0.x), (_Float16)(xi0.y * xj0.y),
                 (_Float16)(xi0.z * xj0.z), (_Float16)(xi0.w * xj0.w),
                 (_Float16)(xi1.x * xj1.x), (_Float16)(xi1.y * xj1.y),
                 (_Float16)(xi1.z * xj1.z), (_Float16)(xi1.w * xj1.w)};
      *(half8*)(&As[j][k8]) = p;
    }
  }
  __syncthreads();

  // ---- K loop, 8 flat steps with 1-deep ping-pong B-frag prefetch ----
  {
    int hbase = 64 * w + c16;
    U16 bgA[4], bgB[4];
#pragma unroll
    for (int ht2 = 0; ht2 < 4; ++ht2)
      bgA[ht2].u = WmT2[quad * 256 + hbase + 16 * ht2];    // it=0
#pragma unroll 1
    for (int it2 = 0; it2 < 4; ++it2) {
      int itE = it2 * 2, itO = itE + 1;
#pragma unroll
      for (int ht2 = 0; ht2 < 4; ++ht2)
        bgB[ht2].u = WmT2[(itO * 4 + quad) * 256 + hbase + 16 * ht2];
      {
        half8 af[4];
#pragma unroll
        for (int jt2 = 0; jt2 < 4; ++jt2)
          af[jt2] = *(const half8*)(&As[jt2 * 16 + c16][itE * 32 + quad * 8]);
#pragma unroll
        for (int jt2 = 0; jt2 < 4; ++jt2)
#pragma unroll
          for (int ht2 = 0; ht2 < 4; ++ht2)
            acc[jt2][ht2] = __builtin_amdgcn_mfma_f32_16x16x32_f16(
                af[jt2], bgA[ht2].h, acc[jt2][ht2], 0, 0, 0);
      }
      if (it2 < 3) {
#pragma unroll
        for (int ht2 = 0; ht2 < 4; ++ht2)
          bgA[ht2].u = WmT2[((itE + 2) * 4 + quad) * 256 + hbase + 16 * ht2];
      }
      {
        half8 af[4];
#pragma unroll
        for (int jt2 = 0; jt2 < 4; ++jt2)
          af[jt2] = *(const half8*)(&As[jt2 * 16 + c16][itO * 32 + quad * 8]);
#pragma unroll
        for (int jt2 = 0; jt2 < 4; ++jt2)
#pragma unroll
          for (int ht2 = 0; ht2 < 4; ++ht2)
            acc[jt2][ht2] = __builtin_amdgcn_mfma_f32_16x16x32_f16(
                af[jt2], bgB[ht2].h, acc[jt2][ht2], 0, 0, 0);
      }
    }
  }

  __syncthreads();  // all A-frag reads done before P overwrites As

  // ---- P = tanh(acc) -> f16 into As (tanh via v_rcp, no precise div) ----
#pragma unroll
  for (int jt2 = 0; jt2 < 4; ++jt2) {
#pragma unroll
    for (int ht2 = 0; ht2 < 4; ++ht2) {
      int hp = 64 * w + 16 * ht2 + c16;
#pragma unroll
      for (int r = 0; r < 4; ++r) {
        int jl = jt2 * 16 + quad * 4 + r;
        float x = acc[jt2][ht2][r];
        float e = __expf(2.f * x);                       // inf-safe
        float t = fmaf(-2.f, __builtin_amdgcn_rcpf(e + 1.f), 1.f);
        As[jl][hp] = (_Float16)t;
      }
    }
  }
  __syncthreads();

  // ---- epilogue GEMM (all 4 waves): rows [16w,16w+16) x 16c, K=256 ----
  {
    U16 wog[8];
#pragma unroll
    for (int s = 0; s < 8; ++s) wog[s].u = WoPk[(s * 4 + quad) * 16 + c16];
    floatx4 accE = {0.f, 0.f, 0.f, 0.f};
#pragma unroll
    for (int s = 0; s < 8; ++s) {
      half8 ae = *(const half8*)(&As[16 * w + c16][s * 32 + quad * 8]);
      accE = __builtin_amdgcn_mfma_f32_16x16x32_f16(ae, wog[s].h, accE, 0, 0, 0);
    }
    const int* mb = mask + b * 256;
    int mi = mb[i];
    int jg0 = j0 + 16 * w + quad * 4;
    int mj[4];
    *(int4*)mj = *(const int4*)(mb + jg0);
    float wob = (c16 < 5) ? Wob[c16] : 0.f;
    float4 v;
#pragma unroll
    for (int r = 0; r < 4; ++r) {
      int jg = jg0 + r;
      float x = accE[r] + wob;
      if (!(mi && mj[r])) x = -INFINITY;
      if (jg < i) x -= 1e12f;
      ((float*)&v)[r] = x;
    }
    if (c16 < 5)
      *(float4*)(&out[(((size_t)b * 5 + c16) * 256 + i) * 256 + jg0]) = v;
  }
}

extern "C" void kernel_launch(void* const* d_in, const int* in_sizes, int n_in,
                              void* d_out, int out_size, void* d_ws, size_t ws_size,
                              hipStream_t stream) {
  const float* hs   = (const float*)d_in[0];
  const int*   mask = (const int*)d_in[1];
  const float* Wh_w = (const float*)d_in[2];
  const float* Wh_b = (const float*)d_in[3];
  const float* Wo_w = (const float*)d_in[4];
  const float* Wo_b = (const float*)d_in[5];

  char* ws = (char*)d_ws;
  float* R    = (float*)(ws + 0);        //  256*256*4  = 262144
  float* a    = (float*)(ws + 262144);   //  512*256*4  = 524288
  float* bv   = (float*)(ws + 786432);   //  512*256*4  = 524288
  uint4* WmT2 = (uint4*)(ws + 1310720);  //  256*256*2  = 131072
  uint4* WoPk = (uint4*)(ws + 1441792);  //  512*16     =   8192
  float* Rp   = (float*)(ws + 1449984);  // 8*65536*4   = 2097152
  float* ap   = (float*)(ws + 3547136);  // 4*131072*4  = 2097152
  float* bp   = (float*)(ws + 5644288);  // 4*131072*4  = 2097152
  int*   cnt  = (int*)(ws + 7741440);    // 192*4       =     768  (end ~7.4MB)

  hipMemsetAsync(cnt, 0, 192 * sizeof(int), stream);
  k_prep<<<1029, 256, 0, stream>>>(hs, Wh_w, Wo_w, Rp, ap, bp, R, a, bv,
                                   WmT2, WoPk, cnt);
  k_main<<<2048, 256, 0, stream>>>(hs, mask, R, a, bv, Wh_b, WmT2, WoPk, Wo_b,
                                   (float*)d_out);
}

// Round 10
// 113.492 us; speedup vs baseline: 2.1038x; 2.1038x over previous
//
#include <hip/hip_runtime.h>
#include <math.h>

typedef _Float16 half8 __attribute__((ext_vector_type(8)));
typedef _Float16 half4v __attribute__((ext_vector_type(4)));
typedef float floatx4 __attribute__((ext_vector_type(4)));

union U16 { uint4 u; half8 h; };

// ---------------------------------------------------------------------------
// k_prep: 261 blocks x 512 thr (8 waves). ONE launch, no partials in HBM,
// no atomics, NO device fences (R9 lesson: device-scope __threadfence on
// 8-XCD gfx950 serializes via L2 writeback -> 170us). K-split is done
// ACROSS WAVES inside a block, reduced via LDS; each wave reproduces one
// of the old cross-block partials with identical k-chunks, and the final
// sum is chunk-ascending -> bit-identical R/a/bv to the old prep1+prep2.
//  [0,128):   R rows d = 2*bid + {0,1}: wave w = chunk kq=w (K=128 serial),
//             red[8][2][256] LDS, final = sum w ascending.
//  [128,256): a/bv rows r0=4*(bid-128)+{0..3}: wave w -> kq=w&3 (K=64),
//             row-pair rp=w>>2; redA/redB[4][4][256], final = kq ascending.
//  [256,260): WmT2 pack granules (f16)
//  [260]:     WoPk pack granules (f16)
// ---------------------------------------------------------------------------
__global__ __launch_bounds__(512) void k_prep(
    const float* __restrict__ hs, const float* __restrict__ Wh,
    const float* __restrict__ Wo,
    float* __restrict__ R, float* __restrict__ a, float* __restrict__ bv,
    uint4* __restrict__ WmT2, uint4* __restrict__ WoPk)
{
  __shared__ __align__(16) char pool[32768];
  int bid = blockIdx.x, tid = threadIdx.x;
  int w = tid >> 6, lane = tid & 63;

  if (bid < 128) {                       // ---- R, 2 d-rows ----
    float (*tbl2)[2] = (float(*)[2])pool;                   // [1024][2] 8KB
    float (*red)[2][256] = (float(*)[2][256])(pool + 8192); // [8][2][256] 16KB
    int d0 = bid * 2;
#pragma unroll
    for (int s = 0; s < 4; ++s) {
      int idx = s * 512 + tid;           // idx = k*2 + dl
      int k = idx >> 1, dl = idx & 1;
      float e = (float)(k & ~1) * (1.0f / 1024.f);
      float div = powf(10000.f, e);
      float ang = (float)(d0 + dl) / div;
      tbl2[k][dl] = (k & 1) ? cosf(ang) : sinf(ang);
    }
    __syncthreads();
    int h0 = lane * 4, k0 = w * 128;     // wave w == old kq chunk
    floatx4 acc0 = {0.f, 0.f, 0.f, 0.f}, acc1 = {0.f, 0.f, 0.f, 0.f};
    for (int kk = 0; kk < 128; ++kk) {
      int k = k0 + kk;
      float4 wv = *(const float4*)(Wh + (size_t)k * 256 + h0);
      float t0 = tbl2[k][0], t1 = tbl2[k][1];
      acc0[0] = fmaf(t0, wv.x, acc0[0]); acc1[0] = fmaf(t1, wv.x, acc1[0]);
      acc0[1] = fmaf(t0, wv.y, acc0[1]); acc1[1] = fmaf(t1, wv.y, acc1[1]);
      acc0[2] = fmaf(t0, wv.z, acc0[2]); acc1[2] = fmaf(t1, wv.z, acc1[2]);
      acc0[3] = fmaf(t0, wv.w, acc0[3]); acc1[3] = fmaf(t1, wv.w, acc1[3]);
    }
    *(floatx4*)&red[w][0][h0] = acc0;
    *(floatx4*)&red[w][1][h0] = acc1;
    __syncthreads();
    {
      int h = tid & 255, dl = tid >> 8;  // 512 thr = 2 rows x 256 h
      float s = 0.f;
#pragma unroll
      for (int q = 0; q < 8; ++q) s += red[q][dl][h];   // ascending == prep2
      R[(size_t)(d0 + dl) * 256 + h] = s;               // d=255 unused, ok
    }

  } else if (bid < 256) {                // ---- a / bv, 4 rows ----
    float (*redA)[4][256] = (float(*)[4][256])pool;            // [4][4][256]
    float (*redB)[4][256] = (float(*)[4][256])(pool + 16384);  // 16KB each
    int r0 = (bid - 128) * 4;
    int kq = w & 3, rp = w >> 2;
    int k0 = kq * 64, h0 = lane * 4;
    int rA = r0 + rp * 2, rB = rA + 1;
    floatx4 aa0 = {0.f,0.f,0.f,0.f}, bb0 = {0.f,0.f,0.f,0.f};
    floatx4 aa1 = {0.f,0.f,0.f,0.f}, bb1 = {0.f,0.f,0.f,0.f};
    for (int kk = 0; kk < 64; ++kk) {
      int k = k0 + kk;
      float4 we = *(const float4*)(Wh + (size_t)k * 256 + h0);
      float4 ws = *(const float4*)(Wh + (size_t)(256 + k) * 256 + h0);
      float4 wd = *(const float4*)(Wh + (size_t)(512 + k) * 256 + h0);
      float wA0 = we.x + wd.x, wB0 = ws.x - wd.x;
      float wA1 = we.y + wd.y, wB1 = ws.y - wd.y;
      float wA2 = we.z + wd.z, wB2 = ws.z - wd.z;
      float wA3 = we.w + wd.w, wB3 = ws.w - wd.w;
      float x0 = hs[(size_t)rA * 256 + k];   // wave-uniform scalar loads
      float x1 = hs[(size_t)rB * 256 + k];
      aa0[0] = fmaf(x0, wA0, aa0[0]); bb0[0] = fmaf(x0, wB0, bb0[0]);
      aa0[1] = fmaf(x0, wA1, aa0[1]); bb0[1] = fmaf(x0, wB1, bb0[1]);
      aa0[2] = fmaf(x0, wA2, aa0[2]); bb0[2] = fmaf(x0, wB2, bb0[2]);
      aa0[3] = fmaf(x0, wA3, aa0[3]); bb0[3] = fmaf(x0, wB3, bb0[3]);
      aa1[0] = fmaf(x1, wA0, aa1[0]); bb1[0] = fmaf(x1, wB0, bb1[0]);
      aa1[1] = fmaf(x1, wA1, aa1[1]); bb1[1] = fmaf(x1, wB1, bb1[1]);
      aa1[2] = fmaf(x1, wA2, aa1[2]); bb1[2] = fmaf(x1, wB2, bb1[2]);
      aa1[3] = fmaf(x1, wA3, aa1[3]); bb1[3] = fmaf(x1, wB3, bb1[3]);
    }
    *(floatx4*)&redA[kq][rp * 2 + 0][h0] = aa0;
    *(floatx4*)&redA[kq][rp * 2 + 1][h0] = aa1;
    *(floatx4*)&redB[kq][rp * 2 + 0][h0] = bb0;
    *(floatx4*)&redB[kq][rp * 2 + 1][h0] = bb1;
    __syncthreads();
    {
      int h = tid & 255, rr = tid >> 8;  // rows rr*2 + {0,1}
#pragma unroll
      for (int j = 0; j < 2; ++j) {
        int row = rr * 2 + j;
        float sa = 0.f, sb = 0.f;
#pragma unroll
        for (int q = 0; q < 4; ++q) {    // ascending kq == old prep2
          sa += redA[q][row][h];
          sb += redB[q][row][h];
        }
        a[(size_t)(r0 + row) * 256 + h] = sa;
        bv[(size_t)(r0 + row) * 256 + h] = sb;
      }
    }

  } else if (bid < 260) {                // ---- WmT2 pack ----
    _Float16 (*T)[256] = (_Float16(*)[256])pool; // [64 k][256 h] 32KB
    int q = bid - 256;
    for (int idx = tid; idx < 16384; idx += 512) {
      int k = idx >> 8, h = idx & 255;
      T[k][h] = (_Float16)Wh[(768 + q * 64 + k) * 256 + h];
    }
    __syncthreads();
    for (int gi = tid; gi < 2048; gi += 512) {
      int kbl = gi >> 8, h = gi & 255;
      U16 v;
#pragma unroll
      for (int e = 0; e < 8; ++e) v.h[e] = T[kbl * 8 + e][h];
      WmT2[(q * 8 + kbl) * 256 + h] = v.u;
    }

  } else {                               // ---- WoPk pack ----
    if (tid < 512) {
      int kb = tid >> 4, c = tid & 15;
      U16 v;
#pragma unroll
      for (int e = 0; e < 8; ++e)
        v.h[e] = (c < 5) ? (_Float16)Wo[(kb * 8 + e) * 5 + c] : (_Float16)0.f;
      WoPk[tid] = v.u;
    }
  }
}

// ---------------------------------------------------------------------------
// main: 2048 blocks = (b, i, j-tile 64); 4 waves, wave w owns h' [64w,64w+64).
// R2 structure (staged coalesced init, padded LDS 34304, bounds(256,4))
// + 1-deep ping-pong B-frag prefetch (R8: k_main dropped below 40.5us).
// [R7: per-lane float4 gathers of bv/R are 1KB-strided -> must stage via LDS.
//  R4: min-waves=5 caps VGPR at 96 -> spill; stay at (256,4).]
// ---------------------------------------------------------------------------
__global__ __launch_bounds__(256, 4) void k_main(
    const float* __restrict__ hs, const int* __restrict__ mask,
    const float* __restrict__ R, const float* __restrict__ a,
    const float* __restrict__ bvec, const float* __restrict__ Whb,
    const uint4* __restrict__ WmT2, const uint4* __restrict__ WoPk,
    const float* __restrict__ Wob, float* __restrict__ out)
{
  __shared__ __align__(16) char smem[34304];          // max(34304, 33792)
  _Float16 (*As)[264] = (_Float16(*)[264])smem;       // [64][264] f16, 33792 B
  float (*stg)[268] = (float(*)[268])smem;            // [32][268] f32, 34304 B

  int bid = blockIdx.x, tid = threadIdx.x;
  int jt = bid & 3, i = (bid >> 2) & 255, b = bid >> 10;
  int j0 = jt * 64;
  int lane = tid & 63, w = tid >> 6;
  int c16 = lane & 15, quad = lane >> 4;
  const float* hsb = hs + (size_t)b * 65536;

  // ---- per-thread constant part of init: a_i + bias ----
  float av[4];
#pragma unroll
  for (int ht2 = 0; ht2 < 4; ++ht2) {
    int hp = 64 * w + 16 * ht2 + c16;
    av[ht2] = a[((size_t)(b * 256 + i)) * 256 + hp] + Whb[hp];
  }

  // ---- acc init via LDS-staged (bv_j + R_d), two 32-row halves ----
  floatx4 acc[4][4];
#pragma unroll
  for (int hf = 0; hf < 2; ++hf) {
    int jbase = j0 + hf * 32;
#pragma unroll
    for (int it = 0; it < 8; ++it) {
      int idx = it * 256 + tid;
      int row = idx >> 6;            // 0..31
      int c4 = (idx & 63) << 2;      // 0..252 step 4
      int jg = jbase + row;
      int dd = jg - i;
      dd = dd < -127 ? -127 : (dd > 127 ? 127 : dd);
      dd += 127;
      float4 bb = *(const float4*)(bvec + ((size_t)(b * 256 + jg)) * 256 + c4);
      float4 rr = *(const float4*)(R + (size_t)dd * 256 + c4);
      float4 s;
      s.x = bb.x + rr.x; s.y = bb.y + rr.y;
      s.z = bb.z + rr.z; s.w = bb.w + rr.w;
      *(float4*)&stg[row][c4] = s;
    }
    __syncthreads();
#pragma unroll
    for (int jj = 0; jj < 2; ++jj) {
      int jt2 = hf * 2 + jj;
#pragma unroll
      for (int r = 0; r < 4; ++r) {
        int jl32 = jj * 16 + quad * 4 + r;
#pragma unroll
        for (int ht2 = 0; ht2 < 4; ++ht2)
          acc[jt2][ht2][r] = av[ht2] + stg[jl32][64 * w + 16 * ht2 + c16];
      }
    }
    __syncthreads();  // stg reads done before next stage / A-tile overwrite
  }

  // ---- A tile: As[j][k] = f16(x_i[k] * x_j[k]), 16B granules ----
  {
    int k8 = (tid & 31) * 8;
    float4 xi0 = *(const float4*)(hsb + i * 256 + k8);
    float4 xi1 = *(const float4*)(hsb + i * 256 + k8 + 4);
    int j = tid >> 5;  // 0..7
#pragma unroll
    for (int s = 0; s < 8; ++s, j += 8) {
      float4 xj0 = *(const float4*)(hsb + (j0 + j) * 256 + k8);
      float4 xj1 = *(const float4*)(hsb + (j0 + j) * 256 + k8 + 4);
      half8 p = {(_Float16)(xi0.x * xj0.x), (_Float16)(xi0.y * xj0.y),
                 (_Float16)(xi0.z * xj0.z), (_Float16)(xi0.w * xj0.w),
                 (_Float16)(xi1.x * xj1.x), (_Float16)(xi1.y * xj1.y),
                 (_Float16)(xi1.z * xj1.z), (_Float16)(xi1.w * xj1.w)};
      *(half8*)(&As[j][k8]) = p;
    }
  }
  __syncthreads();

  // ---- K loop, 8 flat steps with 1-deep ping-pong B-frag prefetch ----
  {
    int hbase = 64 * w + c16;
    U16 bgA[4], bgB[4];
#pragma unroll
    for (int ht2 = 0; ht2 < 4; ++ht2)
      bgA[ht2].u = WmT2[quad * 256 + hbase + 16 * ht2];    // it=0
#pragma unroll 1
    for (int it2 = 0; it2 < 4; ++it2) {
      int itE = it2 * 2, itO = itE + 1;
#pragma unroll
      for (int ht2 = 0; ht2 < 4; ++ht2)
        bgB[ht2].u = WmT2[(itO * 4 + quad) * 256 + hbase + 16 * ht2];
      {
        half8 af[4];
#pragma unroll
        for (int jt2 = 0; jt2 < 4; ++jt2)
          af[jt2] = *(const half8*)(&As[jt2 * 16 + c16][itE * 32 + quad * 8]);
#pragma unroll
        for (int jt2 = 0; jt2 < 4; ++jt2)
#pragma unroll
          for (int ht2 = 0; ht2 < 4; ++ht2)
            acc[jt2][ht2] = __builtin_amdgcn_mfma_f32_16x16x32_f16(
                af[jt2], bgA[ht2].h, acc[jt2][ht2], 0, 0, 0);
      }
      if (it2 < 3) {
#pragma unroll
        for (int ht2 = 0; ht2 < 4; ++ht2)
          bgA[ht2].u = WmT2[((itE + 2) * 4 + quad) * 256 + hbase + 16 * ht2];
      }
      {
        half8 af[4];
#pragma unroll
        for (int jt2 = 0; jt2 < 4; ++jt2)
          af[jt2] = *(const half8*)(&As[jt2 * 16 + c16][itO * 32 + quad * 8]);
#pragma unroll
        for (int jt2 = 0; jt2 < 4; ++jt2)
#pragma unroll
          for (int ht2 = 0; ht2 < 4; ++ht2)
            acc[jt2][ht2] = __builtin_amdgcn_mfma_f32_16x16x32_f16(
                af[jt2], bgB[ht2].h, acc[jt2][ht2], 0, 0, 0);
      }
    }
  }

  __syncthreads();  // all A-frag reads done before P overwrites As

  // ---- P = tanh(acc) -> f16 into As (tanh via v_rcp, no precise div) ----
#pragma unroll
  for (int jt2 = 0; jt2 < 4; ++jt2) {
#pragma unroll
    for (int ht2 = 0; ht2 < 4; ++ht2) {
      int hp = 64 * w + 16 * ht2 + c16;
#pragma unroll
      for (int r = 0; r < 4; ++r) {
        int jl = jt2 * 16 + quad * 4 + r;
        float x = acc[jt2][ht2][r];
        float e = __expf(2.f * x);                       // inf-safe
        float t = fmaf(-2.f, __builtin_amdgcn_rcpf(e + 1.f), 1.f);
        As[jl][hp] = (_Float16)t;
      }
    }
  }
  __syncthreads();

  // ---- epilogue GEMM (all 4 waves): rows [16w,16w+16) x 16c, K=256 ----
  {
    U16 wog[8];
#pragma unroll
    for (int s = 0; s < 8; ++s) wog[s].u = WoPk[(s * 4 + quad) * 16 + c16];
    floatx4 accE = {0.f, 0.f, 0.f, 0.f};
#pragma unroll
    for (int s = 0; s < 8; ++s) {
      half8 ae = *(const half8*)(&As[16 * w + c16][s * 32 + quad * 8]);
      accE = __builtin_amdgcn_mfma_f32_16x16x32_f16(ae, wog[s].h, accE, 0, 0, 0);
    }
    const int* mb = mask + b * 256;
    int mi = mb[i];
    int jg0 = j0 + 16 * w + quad * 4;
    int mj[4];
    *(int4*)mj = *(const int4*)(mb + jg0);
    float wob = (c16 < 5) ? Wob[c16] : 0.f;
    float4 v;
#pragma unroll
    for (int r = 0; r < 4; ++r) {
      int jg = jg0 + r;
      float x = accE[r] + wob;
      if (!(mi && mj[r])) x = -INFINITY;
      if (jg < i) x -= 1e12f;
      ((float*)&v)[r] = x;
    }
    if (c16 < 5)
      *(float4*)(&out[(((size_t)b * 5 + c16) * 256 + i) * 256 + jg0]) = v;
  }
}

extern "C" void kernel_launch(void* const* d_in, const int* in_sizes, int n_in,
                              void* d_out, int out_size, void* d_ws, size_t ws_size,
                              hipStream_t stream) {
  const float* hs   = (const float*)d_in[0];
  const int*   mask = (const int*)d_in[1];
  const float* Wh_w = (const float*)d_in[2];
  const float* Wh_b = (const float*)d_in[3];
  const float* Wo_w = (const float*)d_in[4];
  const float* Wo_b = (const float*)d_in[5];

  char* ws = (char*)d_ws;
  float* R    = (float*)(ws + 0);        //  256*256*4  = 262144
  float* a    = (float*)(ws + 262144);   //  512*256*4  = 524288
  float* bv   = (float*)(ws + 786432);   //  512*256*4  = 524288
  uint4* WmT2 = (uint4*)(ws + 1310720);  //  256*256*2  = 131072
  uint4* WoPk = (uint4*)(ws + 1441792);  //  512*16     =   8192  (end ~1.45MB)

  k_prep<<<261, 512, 0, stream>>>(hs, Wh_w, Wo_w, R, a, bv, WmT2, WoPk);
  k_main<<<2048, 256, 0, stream>>>(hs, mask, R, a, bv, Wh_b, WmT2, WoPk, Wo_b,
                                   (float*)d_out);
}